// Round 26
// baseline (82.394 us; speedup 1.0000x reference)
//
#include <hip/hip_runtime.h>

// Exponential smoothing: s[-1]=v0; s[j] = w*s[j-1] + (1-w)*x[j]; out[j]=s[j]
// w = sigmoid(smoothing_weight[h]).
// Round-26: CHUNK-PAIRED single-generation grid. r14/r25 analysis: 1024
// blocks x 16 waves = 2 generations at 2 blocks/CU -> load stream serialized
// 2x (3.4 TB/s ~ half of 6.9 fill ceiling). Fix: block (b,q) owns chunks
// c0=2q, c1=2q+1 -> 512 blocks = ONE generation.
//   - c0: loaded into pinned regs (r14 path: load/fold/publish/walk/scan)
//   - c1: STREAM-folded in phase 1 (fold A1, discard) so BOTH aggs publish
//     early (keeps r14's shallow poll-dependency profile); carry1 =
//     Wc*carry0 + Ab0 is LOCAL (no polls; halves poll count per byte);
//     c1 re-read at scan time from L3 (just touched; NT out-stores don't
//     evict values).
// Inter-block comm: relaxed agent atomics + 0xFFFFFFFF sentinel only; sg
// producers publish before polling sgs; ticket keeps dep-order=dispatch
// order. Fixed-order folds => bit-deterministic (same algebra as r14).

namespace {

constexpr int Bt   = 16;          // batch
constexpr int Tt   = 4096;        // time
constexpr int HD4  = 128;         // float4 channels per (b,t)
constexpr int CL   = 64;          // chunk length
constexpr int NGRP = 8;           // time-groups per chunk
constexpr int TS   = CL / NGRP;   // 8 steps per group
constexpr int NC   = Tt / CL;     // 64 chunks per batch
constexpr int NPAIR = NC / 2;     // 32 pairs per batch
constexpr int NBLK = NPAIR * Bt;  // 512 blocks (single generation)
constexpr int NTHR = NGRP * HD4;  // 1024 threads
constexpr unsigned SENT = 0xFFFFFFFFu;

typedef float fvec4 __attribute__((ext_vector_type(4)));

__device__ __forceinline__ float sigmoidf_(float x) {
    return 1.0f / (1.0f + expf(-x));
}

__device__ __forceinline__ unsigned ld_relaxed(const unsigned* p) {
    return __hip_atomic_load(p, __ATOMIC_RELAXED, __HIP_MEMORY_SCOPE_AGENT);
}

__device__ __forceinline__ float poll1(const unsigned* p) {
    unsigned u = ld_relaxed(p);
    while (u == SENT) {
        __builtin_amdgcn_s_sleep(2);
        u = ld_relaxed(p);
    }
    return __uint_as_float(u);
}

__device__ __forceinline__ void store1(float* p, float v) {
    __hip_atomic_store(p, v, __ATOMIC_RELAXED, __HIP_MEMORY_SCOPE_AGENT);
}

__device__ __forceinline__ void store4(float* p, const float4& v) {
    store1(p + 0, v.x); store1(p + 1, v.y);
    store1(p + 2, v.z); store1(p + 3, v.w);
}

__global__ __launch_bounds__(NTHR, 8) void ema_pair(
    const float4* __restrict__ values4, const float* __restrict__ sw,
    const float* __restrict__ v0f, float4* __restrict__ out4,
    float* __restrict__ aggf, float* __restrict__ sgf,
    int* __restrict__ ticket) {

    __shared__ float4 s_A0[NGRP][HD4];   // 16 KiB c0 group partials
    __shared__ float4 s_A1[NGRP][HD4];   // 16 KiB c1 group partials
    __shared__ float4 s_Ab0[HD4];        // 2 KiB c0 block aggregate
    __shared__ float4 s_Ab1[HD4];        // 2 KiB c1 block aggregate
    __shared__ float  s_c0[512];         // 2 KiB carry entering c0
    __shared__ float  s_c1[512];         // 2 KiB carry entering c1
    __shared__ int s_vid;

    const int tid = threadIdx.x;
    if (tid == 0) s_vid = atomicAdd(ticket, 1);
    __syncthreads();
    const int vid = s_vid;
    const int b = vid & (Bt - 1);
    const int q = vid >> 4;              // pair index; deps have lower vid
    const int c0 = 2 * q;
    const int c1 = 2 * q + 1;
    const int ch = tid & (HD4 - 1);
    const int g  = tid >> 7;             // time-group 0..7, wave-uniform

    const float w   = sigmoidf_(sw[ch >> 4]);
    const float omw = 1.0f - w;
    float W8 = w * w;  W8 = W8 * W8;  W8 = W8 * W8;       // w^8

    // Phase 1a: load c0's 8 steps into pinned regs; fold zero-seed partial.
    const size_t base0 =
        ((size_t)b * Tt + (size_t)c0 * CL + (size_t)g * TS) * HD4 + ch;
    const size_t base1 =
        ((size_t)b * Tt + (size_t)c1 * CL + (size_t)g * TS) * HD4 + ch;
    const float4* p0 = values4 + base0;
    const float4* p1 = values4 + base1;

    float4 x[TS];
    float4 A0 = make_float4(0.f, 0.f, 0.f, 0.f);
    #pragma unroll
    for (int u = 0; u < TS; ++u) {
        x[u] = p0[(size_t)u * HD4];
        A0.x = fmaf(w, A0.x, omw * x[u].x);
        A0.y = fmaf(w, A0.y, omw * x[u].y);
        A0.z = fmaf(w, A0.z, omw * x[u].z);
        A0.w = fmaf(w, A0.w, omw * x[u].w);
    }
    #pragma unroll
    for (int u = 0; u < TS; ++u)
        asm volatile("" : "+v"(x[u].x), "+v"(x[u].y), "+v"(x[u].z), "+v"(x[u].w));

    // Phase 1b: STREAM-fold c1 (values folded and discarded; re-read later).
    float4 A1 = make_float4(0.f, 0.f, 0.f, 0.f);
    #pragma unroll
    for (int u = 0; u < TS; ++u) {
        float4 xv = p1[(size_t)u * HD4];
        A1.x = fmaf(w, A1.x, omw * xv.x);
        A1.y = fmaf(w, A1.y, omw * xv.y);
        A1.z = fmaf(w, A1.z, omw * xv.z);
        A1.w = fmaf(w, A1.w, omw * xv.w);
    }
    s_A0[g][ch] = A0;
    s_A1[g][ch] = A1;
    __syncthreads();   // barrier 1

    // Phase 2: last group folds BOTH block aggregates; publishes both aggs.
    if (g == NGRP - 1) {
        float4 t0 = s_A0[0][ch];
        float4 t1 = s_A1[0][ch];
        #pragma unroll
        for (int j = 1; j < NGRP; ++j) {
            float4 Aj0 = s_A0[j][ch];
            float4 Aj1 = s_A1[j][ch];
            t0.x = fmaf(W8, t0.x, Aj0.x);
            t0.y = fmaf(W8, t0.y, Aj0.y);
            t0.z = fmaf(W8, t0.z, Aj0.z);
            t0.w = fmaf(W8, t0.w, Aj0.w);
            t1.x = fmaf(W8, t1.x, Aj1.x);
            t1.y = fmaf(W8, t1.y, Aj1.y);
            t1.z = fmaf(W8, t1.z, Aj1.z);
            t1.w = fmaf(W8, t1.w, Aj1.w);
        }
        s_Ab0[ch] = t0;
        s_Ab1[ch] = t1;
        store4(aggf + (((size_t)c0 * Bt + b) * HD4 + ch) * 4, t0);
        store4(aggf + (((size_t)c1 * Bt + b) * HD4 + ch) * 4, t1);
    }
    __syncthreads();   // barrier 2

    // Phase 3: carry walk (threads 0..511, one float channel each).
    if (tid < 512) {
        const float ws = sigmoidf_(sw[tid >> 6]);
        float Wcs = ws * ws;
        #pragma unroll
        for (int i = 0; i < 5; ++i) Wcs = Wcs * Wcs;           // w^64
        float WSGs = Wcs;
        #pragma unroll
        for (int i = 0; i < 3; ++i) WSGs = WSGs * WSGs;        // w^512

        const unsigned* au = (const unsigned*)aggf;
        const unsigned* su = (const unsigned*)sgf;
        const int mf   = c0 >> 3;        // complete supergroups (SG=8)
        const int k0   = mf << 3;
        const int rem0 = c0 - k0;        // even: 0,2,4,6

        // Remainder scan R over aggs [k0, c0): polls, <=6 (all early-pub).
        float R = 0.0f;
        #pragma unroll
        for (int j = 0; j < 6; ++j) {
            if (k0 + j < c0) {
                float av = poll1(au + ((size_t)(k0 + j) * Bt + b) * (HD4 * 4) + tid);
                R = fmaf(Wcs, R, av);
            }
        }

        const float ab0 = ((const float*)s_Ab0)[tid];
        // sg producer (c1&7==7 <=> rem0==6): publish inclusive [k0..c1] fold.
        if (rem0 == 6) {
            const float ab1 = ((const float*)s_Ab1)[tid];
            float z = fmaf(Wcs, R, ab0);       // fold through c0
            z = fmaf(Wcs, z, ab1);             // fold through c1
            store1(sgf + ((size_t)mf * Bt + b) * (HD4 * 4) + tid, z);
            asm volatile("" ::: "memory");
        }

        // Supergroup prefix P (seed v0): polls <= 7.
        float P = v0f[tid];
        #pragma unroll
        for (int j = 0; j < 7; ++j) {
            if (j < mf) {
                float svv = poll1(su + ((size_t)j * Bt + b) * (HD4 * 4) + tid);
                P = fmaf(WSGs, P, svv);
            }
        }

        // carry0 = Wc^rem0 * P + R; carry1 = Wc*carry0 + Ab0 (LOCAL).
        float Wr = 1.0f, pw = Wcs;
        if (rem0 & 1) Wr *= pw;  pw *= pw;
        if (rem0 & 2) Wr *= pw;  pw *= pw;
        if (rem0 & 4) Wr *= pw;
        const float cr0 = fmaf(Wr, P, R);
        s_c0[tid] = cr0;
        s_c1[tid] = fmaf(Wcs, cr0, ab0);
    }
    __syncthreads();   // barrier 3

    // Phase 4: scan c0 from pinned regs; NT store.
    float4 s0;
    s0.x = s_c0[4 * ch + 0]; s0.y = s_c0[4 * ch + 1];
    s0.z = s_c0[4 * ch + 2]; s0.w = s_c0[4 * ch + 3];
    #pragma unroll
    for (int j = 0; j < NGRP - 1; ++j) {
        if (j < g) {
            float4 Aj = s_A0[j][ch];
            s0.x = fmaf(W8, s0.x, Aj.x);
            s0.y = fmaf(W8, s0.y, Aj.y);
            s0.z = fmaf(W8, s0.z, Aj.z);
            s0.w = fmaf(W8, s0.w, Aj.w);
        }
    }
    fvec4* q0 = (fvec4*)(out4 + base0);
    #pragma unroll
    for (int u = 0; u < TS; ++u) {
        s0.x = fmaf(w, s0.x, omw * x[u].x);
        s0.y = fmaf(w, s0.y, omw * x[u].y);
        s0.z = fmaf(w, s0.z, omw * x[u].z);
        s0.w = fmaf(w, s0.w, omw * x[u].w);
        fvec4 sn = {s0.x, s0.y, s0.z, s0.w};
        __builtin_nontemporal_store(sn, q0 + (size_t)u * HD4);
    }

    // Phase 5: re-read c1 (L3-fresh), scan, NT store.
    float4 s1;
    s1.x = s_c1[4 * ch + 0]; s1.y = s_c1[4 * ch + 1];
    s1.z = s_c1[4 * ch + 2]; s1.w = s_c1[4 * ch + 3];
    #pragma unroll
    for (int j = 0; j < NGRP - 1; ++j) {
        if (j < g) {
            float4 Aj = s_A1[j][ch];
            s1.x = fmaf(W8, s1.x, Aj.x);
            s1.y = fmaf(W8, s1.y, Aj.y);
            s1.z = fmaf(W8, s1.z, Aj.z);
            s1.w = fmaf(W8, s1.w, Aj.w);
        }
    }
    fvec4* q1 = (fvec4*)(out4 + base1);
    #pragma unroll
    for (int u = 0; u < TS; ++u) {
        float4 xv = p1[(size_t)u * HD4];
        s1.x = fmaf(w, s1.x, omw * xv.x);
        s1.y = fmaf(w, s1.y, omw * xv.y);
        s1.z = fmaf(w, s1.z, omw * xv.z);
        s1.w = fmaf(w, s1.w, omw * xv.w);
        fvec4 sn = {s1.x, s1.y, s1.z, s1.w};
        __builtin_nontemporal_store(sn, q1 + (size_t)u * HD4);
    }
}

}  // namespace

extern "C" void kernel_launch(void* const* d_in, const int* in_sizes, int n_in,
                              void* d_out, int out_size, void* d_ws, size_t ws_size,
                              hipStream_t stream) {
    const float4* values4 = (const float4*)d_in[0];  // [16, 4096, 8, 64] f32
    const float*  sw      = (const float*)d_in[1];   // [8, 1]
    const float*  v0f     = (const float*)d_in[2];   // [1, 1, 8, 64] = 512 f32
    float4* out4 = (float4*)d_out;

    const size_t aggFloats = (size_t)NC * Bt * HD4 * 4;        // 2 MiB
    const size_t sgFloats  = (size_t)(NC / 8) * Bt * HD4 * 4;  // 256 KiB
    float* aggf   = (float*)d_ws;
    float* sgf    = aggf + aggFloats;
    int*   ticket = (int*)(sgf + sgFloats);

    (void)hipMemsetAsync(aggf, 0xFF, (aggFloats + sgFloats) * sizeof(float), stream);
    (void)hipMemsetAsync(ticket, 0, sizeof(int), stream);

    ema_pair<<<dim3(NBLK), dim3(NTHR), 0, stream>>>(values4, sw, v0f, out4,
                                                    aggf, sgf, ticket);
}

// Round 27
// 64.543 us; speedup vs baseline: 1.2766x; 1.2766x over previous
//
#include <hip/hip_runtime.h>

// Exponential smoothing: s[-1]=v0; s[j] = w*s[j-1] + (1-w)*x[j]; out[j]=s[j]
// w = sigmoid(smoothing_weight[h]).
// FINAL (restored round-14): measured best — 61.9 us (r14), 65.6 us (r25
// reconfirm) across 3 design families and 16 measured variants.
// Single-pass chained scan; values read ONCE, out written ONCE.
//   - 1024-thread blocks, 8 groups x 128 float4-ch, TS=8 steps/thread
//   - grid 1024 blocks (CL=64, NC=64); hierarchical carry walk <=7 sg +
//     <=7 chunk polls (serial poll-and-fold, threads 0..511)
//   - inter-block comm: relaxed agent atomics + 0xFFFFFFFF sentinel only
//     (no fences -> no L2 wb/inv storms); sg producers publish before
//     polling sgs; ticket keeps dependency-order = dispatch-order
//   - fixed-order folds => bit-deterministic
// Falsified levers (each <2us or regression): occupancy max (r16-r21),
// spill elimination (r12/r14/r20), LDS staging (r7/r9/r18), walk shape
// (r10/r12), NT-store L3 retention (r15/r19), zero-sync multi-kernel
// (r15/r19), single-generation chunk-pairing (r26: +20us, re-read not
// L3-served). Remaining gap to the 43us copy-roofline is the
// phase-serialized dependency critical path + the allocator's hard
// refusal to hold >16 pinned VGPRs across sync points.

namespace {

constexpr int Bt   = 16;          // batch
constexpr int Tt   = 4096;        // time
constexpr int HD4  = 128;         // float4 channels per (b,t)
constexpr int CL   = 64;          // chunk length
constexpr int NGRP = 8;           // time-groups per chunk
constexpr int TS   = CL / NGRP;   // 8 steps per group
constexpr int NC   = Tt / CL;     // 64 chunks per batch
constexpr int NBLK = NC * Bt;     // 1024
constexpr int NTHR = NGRP * HD4;  // 1024 threads
constexpr unsigned SENT = 0xFFFFFFFFu;

typedef float fvec4 __attribute__((ext_vector_type(4)));

__device__ __forceinline__ float sigmoidf_(float x) {
    return 1.0f / (1.0f + expf(-x));
}

__device__ __forceinline__ unsigned ld_relaxed(const unsigned* p) {
    return __hip_atomic_load(p, __ATOMIC_RELAXED, __HIP_MEMORY_SCOPE_AGENT);
}

__device__ __forceinline__ float poll1(const unsigned* p) {
    unsigned u = ld_relaxed(p);
    while (u == SENT) {
        __builtin_amdgcn_s_sleep(2);
        u = ld_relaxed(p);
    }
    return __uint_as_float(u);
}

__device__ __forceinline__ void store1(float* p, float v) {
    __hip_atomic_store(p, v, __ATOMIC_RELAXED, __HIP_MEMORY_SCOPE_AGENT);
}

__device__ __forceinline__ void store4(float* p, const float4& v) {
    store1(p + 0, v.x); store1(p + 1, v.y);
    store1(p + 2, v.z); store1(p + 3, v.w);
}

__global__ __launch_bounds__(NTHR, 8) void ema_onepass(
    const float4* __restrict__ values4, const float* __restrict__ sw,
    const float* __restrict__ v0f, float4* __restrict__ out4,
    float* __restrict__ aggf, float* __restrict__ sgf,
    int* __restrict__ ticket) {

    __shared__ float4 s_A[NGRP][HD4];    // 16 KiB per-group partial aggs
    __shared__ float4 s_Ab[HD4];         // 2 KiB block aggregate
    __shared__ float4 s_carryv[HD4];     // 2 KiB carry
    __shared__ int s_vid;

    const int tid = threadIdx.x;
    if (tid == 0) s_vid = atomicAdd(ticket, 1);
    __syncthreads();
    const int vid = s_vid;
    const int b = vid & (Bt - 1);
    const int c = vid >> 4;              // chunk; deps have lower vid
    const int ch = tid & (HD4 - 1);
    const int g  = tid >> 7;             // time-group 0..7, wave-uniform

    const float w   = sigmoidf_(sw[ch >> 4]);
    const float omw = 1.0f - w;
    float W8 = w * w;  W8 = W8 * W8;  W8 = W8 * W8;       // w^8

    // Load my 8 time-steps into registers; fold zero-seed partial aggregate.
    const size_t chunkbase = ((size_t)b * Tt + (size_t)c * CL) * HD4 + ch;
    const float4* p = values4 + chunkbase + (size_t)g * TS * HD4;
    float4 x[TS];
    float4 A = make_float4(0.f, 0.f, 0.f, 0.f);
    #pragma unroll
    for (int u = 0; u < TS; ++u) {
        x[u] = p[(size_t)u * HD4];
        A.x = fmaf(w, A.x, omw * x[u].x);
        A.y = fmaf(w, A.y, omw * x[u].y);
        A.z = fmaf(w, A.z, omw * x[u].z);
        A.w = fmaf(w, A.w, omw * x[u].w);
    }
    // Pin the chunk (anti-rematerialization, rounds 5/6 lesson).
    #pragma unroll
    for (int u = 0; u < TS; ++u)
        asm volatile("" : "+v"(x[u].x), "+v"(x[u].y), "+v"(x[u].z), "+v"(x[u].w));

    s_A[g][ch] = A;
    __syncthreads();   // barrier 1

    // Last group folds the block aggregate (8 partials) and publishes.
    if (g == NGRP - 1) {
        float4 t = s_A[0][ch];
        #pragma unroll
        for (int j = 1; j < NGRP; ++j) {
            float4 Aj = (j == NGRP - 1) ? A : s_A[j][ch];
            t.x = fmaf(W8, t.x, Aj.x);
            t.y = fmaf(W8, t.y, Aj.y);
            t.z = fmaf(W8, t.z, Aj.z);
            t.w = fmaf(W8, t.w, Aj.w);
        }
        s_Ab[ch] = t;
        store4(aggf + (((size_t)c * Bt + b) * HD4 + ch) * 4, t);
    }
    __syncthreads();   // barrier 2

    // ---- Carry walk: threads 0..511, one float channel each ----
    if (tid < 512) {
        const float ws = sigmoidf_(sw[tid >> 6]);
        float Wcs = ws * ws;
        #pragma unroll
        for (int i = 0; i < 5; ++i) Wcs = Wcs * Wcs;           // w^64
        float WSGs = Wcs;
        #pragma unroll
        for (int i = 0; i < 3; ++i) WSGs = WSGs * WSGs;        // w^512

        const unsigned* au = (const unsigned*)aggf;
        const unsigned* su = (const unsigned*)sgf;
        const int mf  = c >> 3;          // complete supergroups (SG=8)
        const int k0  = mf << 3;
        const int rem = c - k0;          // 0..7

        // Phase 1: remainder scan R (seed 0), serial poll-and-fold.
        float R = 0.0f;
        #pragma unroll
        for (int j = 0; j < 7; ++j) {
            if (k0 + j < c) {
                float av = poll1(au + ((size_t)(k0 + j) * Bt + b) * (HD4 * 4) + tid);
                R = fmaf(Wcs, R, av);
            }
        }

        // Phase 2: supergroup producer publishes immediately (local deps).
        if ((c & 7) == 7) {
            float ab = ((const float*)s_Ab)[tid];
            store1(sgf + ((size_t)mf * Bt + b) * (HD4 * 4) + tid,
                   fmaf(Wcs, R, ab));
            asm volatile("" ::: "memory");
        }

        // Phase 3: supergroup prefix P (seed v0), serial poll-and-fold.
        float P = v0f[tid];
        #pragma unroll
        for (int j = 0; j < 7; ++j) {
            if (j < mf) {
                float svv = poll1(su + ((size_t)j * Bt + b) * (HD4 * 4) + tid);
                P = fmaf(WSGs, P, svv);
            }
        }

        // carry = Wc^rem * P + R   (rem in 0..7)
        float Wr = 1.0f, pw = Wcs;
        if (rem & 1) Wr *= pw;  pw *= pw;
        if (rem & 2) Wr *= pw;  pw *= pw;
        if (rem & 4) Wr *= pw;
        ((float*)s_carryv)[tid] = fmaf(Wr, P, R);
    }
    __syncthreads();   // barrier 3

    // Group seed: fold partial aggs of groups < g onto the carry.
    float4 s = s_carryv[ch];
    #pragma unroll
    for (int j = 0; j < NGRP - 1; ++j) {
        if (j < g) {
            float4 Aj = s_A[j][ch];
            s.x = fmaf(W8, s.x, Aj.x);
            s.y = fmaf(W8, s.y, Aj.y);
            s.z = fmaf(W8, s.z, Aj.z);
            s.w = fmaf(W8, s.w, Aj.w);
        }
    }

    // Final scan from registers; nontemporal stream out.
    fvec4* q = (fvec4*)(out4 + chunkbase + (size_t)g * TS * HD4);
    #pragma unroll
    for (int u = 0; u < TS; ++u) {
        s.x = fmaf(w, s.x, omw * x[u].x);
        s.y = fmaf(w, s.y, omw * x[u].y);
        s.z = fmaf(w, s.z, omw * x[u].z);
        s.w = fmaf(w, s.w, omw * x[u].w);
        fvec4 sn = {s.x, s.y, s.z, s.w};
        __builtin_nontemporal_store(sn, q + (size_t)u * HD4);
    }
}

}  // namespace

extern "C" void kernel_launch(void* const* d_in, const int* in_sizes, int n_in,
                              void* d_out, int out_size, void* d_ws, size_t ws_size,
                              hipStream_t stream) {
    const float4* values4 = (const float4*)d_in[0];  // [16, 4096, 8, 64] f32
    const float*  sw      = (const float*)d_in[1];   // [8, 1]
    const float*  v0f     = (const float*)d_in[2];   // [1, 1, 8, 64] = 512 f32
    float4* out4 = (float4*)d_out;

    const size_t aggFloats = (size_t)NC * Bt * HD4 * 4;        // 2 MiB
    const size_t sgFloats  = (size_t)(NC / 8) * Bt * HD4 * 4;  // 256 KiB
    float* aggf   = (float*)d_ws;
    float* sgf    = aggf + aggFloats;
    int*   ticket = (int*)(sgf + sgFloats);

    (void)hipMemsetAsync(aggf, 0xFF, (aggFloats + sgFloats) * sizeof(float), stream);
    (void)hipMemsetAsync(ticket, 0, sizeof(int), stream);

    ema_onepass<<<dim3(NBLK), dim3(NTHR), 0, stream>>>(values4, sw, v0f, out4,
                                                       aggf, sgf, ticket);
}

// Round 28
// 61.632 us; speedup vs baseline: 1.3369x; 1.0472x over previous
//
#include <hip/hip_runtime.h>

// Exponential smoothing: s[-1]=v0; s[j] = w*s[j-1] + (1-w)*x[j]; out[j]=s[j]
// w = sigmoid(smoothing_weight[h]).
// Round-28 = r14 with a COMPRESSED PUBLISH PATH (last untried micro-lever):
//   - g==7 float4 block-agg fold + s_Ab + barrier-2 DELETED
//   - right after barrier 1, walk threads (0..511) fold their scalar
//     channel's block aggregate from s_A (8 conflict-free scalar LDS reads,
//     same fold order => bit-identical) and publish IMMEDIATELY
//   - publish moves ~(fold+barrier+broadcast) earlier; the saving compounds
//     through the agg -> sg-producer -> sg-consumer dependency chain
// All else identical to r14 (measured 61.9/64.5/65.6 us): 1024 thr blocks,
// CL=64, TS=8, 1024 blocks, ticket order, sentinel relaxed atomics,
// sg-publish-before-sg-poll, pinned x regs, NT out stores.

namespace {

constexpr int Bt   = 16;          // batch
constexpr int Tt   = 4096;        // time
constexpr int HD4  = 128;         // float4 channels per (b,t)
constexpr int CL   = 64;          // chunk length
constexpr int NGRP = 8;           // time-groups per chunk
constexpr int TS   = CL / NGRP;   // 8 steps per group
constexpr int NC   = Tt / CL;     // 64 chunks per batch
constexpr int NBLK = NC * Bt;     // 1024
constexpr int NTHR = NGRP * HD4;  // 1024 threads
constexpr unsigned SENT = 0xFFFFFFFFu;

typedef float fvec4 __attribute__((ext_vector_type(4)));

__device__ __forceinline__ float sigmoidf_(float x) {
    return 1.0f / (1.0f + expf(-x));
}

__device__ __forceinline__ unsigned ld_relaxed(const unsigned* p) {
    return __hip_atomic_load(p, __ATOMIC_RELAXED, __HIP_MEMORY_SCOPE_AGENT);
}

__device__ __forceinline__ float poll1(const unsigned* p) {
    unsigned u = ld_relaxed(p);
    while (u == SENT) {
        __builtin_amdgcn_s_sleep(2);
        u = ld_relaxed(p);
    }
    return __uint_as_float(u);
}

__device__ __forceinline__ void store1(float* p, float v) {
    __hip_atomic_store(p, v, __ATOMIC_RELAXED, __HIP_MEMORY_SCOPE_AGENT);
}

__global__ __launch_bounds__(NTHR, 8) void ema_onepass(
    const float4* __restrict__ values4, const float* __restrict__ sw,
    const float* __restrict__ v0f, float4* __restrict__ out4,
    float* __restrict__ aggf, float* __restrict__ sgf,
    int* __restrict__ ticket) {

    __shared__ float4 s_A[NGRP][HD4];    // 16 KiB per-group partial aggs
    __shared__ float  s_carry[512];      // 2 KiB carry (scalar channels)
    __shared__ int s_vid;

    const int tid = threadIdx.x;
    if (tid == 0) s_vid = atomicAdd(ticket, 1);
    __syncthreads();
    const int vid = s_vid;
    const int b = vid & (Bt - 1);
    const int c = vid >> 4;              // chunk; deps have lower vid
    const int ch = tid & (HD4 - 1);
    const int g  = tid >> 7;             // time-group 0..7, wave-uniform

    const float w   = sigmoidf_(sw[ch >> 4]);
    const float omw = 1.0f - w;
    float W8 = w * w;  W8 = W8 * W8;  W8 = W8 * W8;       // w^8

    // Load my 8 time-steps into registers; fold zero-seed partial aggregate.
    const size_t chunkbase = ((size_t)b * Tt + (size_t)c * CL) * HD4 + ch;
    const float4* p = values4 + chunkbase + (size_t)g * TS * HD4;
    float4 x[TS];
    float4 A = make_float4(0.f, 0.f, 0.f, 0.f);
    #pragma unroll
    for (int u = 0; u < TS; ++u) {
        x[u] = p[(size_t)u * HD4];
        A.x = fmaf(w, A.x, omw * x[u].x);
        A.y = fmaf(w, A.y, omw * x[u].y);
        A.z = fmaf(w, A.z, omw * x[u].z);
        A.w = fmaf(w, A.w, omw * x[u].w);
    }
    // Pin the chunk (anti-rematerialization, rounds 5/6 lesson).
    #pragma unroll
    for (int u = 0; u < TS; ++u)
        asm volatile("" : "+v"(x[u].x), "+v"(x[u].y), "+v"(x[u].z), "+v"(x[u].w));

    s_A[g][ch] = A;
    __syncthreads();   // barrier 1 (s_A ready)

    // ---- Walk threads: fold block agg per scalar channel, publish NOW,
    //      then carry walk. Scalar channel f = tid; s_A viewed as [8][512]
    //      floats is contiguous in tid -> conflict-free LDS reads.
    if (tid < 512) {
        const float ws  = sigmoidf_(sw[tid >> 6]);
        float W8s = ws * ws;  W8s = W8s * W8s;  W8s = W8s * W8s;   // w^8
        float Wcs = W8s * W8s;  Wcs = Wcs * Wcs;  Wcs = Wcs * Wcs; // w^64
        float WSGs = Wcs;
        #pragma unroll
        for (int i = 0; i < 3; ++i) WSGs = WSGs * WSGs;            // w^512

        // Block aggregate: same fold order as r14's g==7 path => bit-equal.
        const float* sa = (const float*)s_A;   // [8][512] floats
        float ab = sa[tid];
        #pragma unroll
        for (int j = 1; j < NGRP; ++j) ab = fmaf(W8s, ab, sa[j * 512 + tid]);

        // Publish immediately (earliest possible point after barrier 1).
        store1(aggf + ((size_t)c * Bt + b) * 512 + tid, ab);

        const unsigned* au = (const unsigned*)aggf;
        const unsigned* su = (const unsigned*)sgf;
        const int mf  = c >> 3;          // complete supergroups (SG=8)
        const int k0  = mf << 3;
        const int rem = c - k0;          // 0..7

        // Phase 1: remainder scan R (seed 0), serial poll-and-fold.
        float R = 0.0f;
        #pragma unroll
        for (int j = 0; j < 7; ++j) {
            if (k0 + j < c) {
                float av = poll1(au + ((size_t)(k0 + j) * Bt + b) * 512 + tid);
                R = fmaf(Wcs, R, av);
            }
        }

        // Phase 2: supergroup producer publishes immediately (local deps).
        if ((c & 7) == 7) {
            store1(sgf + ((size_t)mf * Bt + b) * 512 + tid,
                   fmaf(Wcs, R, ab));
            asm volatile("" ::: "memory");
        }

        // Phase 3: supergroup prefix P (seed v0), serial poll-and-fold.
        float P = v0f[tid];
        #pragma unroll
        for (int j = 0; j < 7; ++j) {
            if (j < mf) {
                float svv = poll1(su + ((size_t)j * Bt + b) * 512 + tid);
                P = fmaf(WSGs, P, svv);
            }
        }

        // carry = Wc^rem * P + R   (rem in 0..7)
        float Wr = 1.0f, pw = Wcs;
        if (rem & 1) Wr *= pw;  pw *= pw;
        if (rem & 2) Wr *= pw;  pw *= pw;
        if (rem & 4) Wr *= pw;
        s_carry[tid] = fmaf(Wr, P, R);
    }
    __syncthreads();   // barrier 2 (carry ready)

    // Group seed: fold partial aggs of groups < g onto the carry.
    float4 s;
    s.x = s_carry[4 * ch + 0];
    s.y = s_carry[4 * ch + 1];
    s.z = s_carry[4 * ch + 2];
    s.w = s_carry[4 * ch + 3];
    #pragma unroll
    for (int j = 0; j < NGRP - 1; ++j) {
        if (j < g) {
            float4 Aj = s_A[j][ch];
            s.x = fmaf(W8, s.x, Aj.x);
            s.y = fmaf(W8, s.y, Aj.y);
            s.z = fmaf(W8, s.z, Aj.z);
            s.w = fmaf(W8, s.w, Aj.w);
        }
    }

    // Final scan from registers; nontemporal stream out.
    fvec4* q = (fvec4*)(out4 + chunkbase + (size_t)g * TS * HD4);
    #pragma unroll
    for (int u = 0; u < TS; ++u) {
        s.x = fmaf(w, s.x, omw * x[u].x);
        s.y = fmaf(w, s.y, omw * x[u].y);
        s.z = fmaf(w, s.z, omw * x[u].z);
        s.w = fmaf(w, s.w, omw * x[u].w);
        fvec4 sn = {s.x, s.y, s.z, s.w};
        __builtin_nontemporal_store(sn, q + (size_t)u * HD4);
    }
}

}  // namespace

extern "C" void kernel_launch(void* const* d_in, const int* in_sizes, int n_in,
                              void* d_out, int out_size, void* d_ws, size_t ws_size,
                              hipStream_t stream) {
    const float4* values4 = (const float4*)d_in[0];  // [16, 4096, 8, 64] f32
    const float*  sw      = (const float*)d_in[1];   // [8, 1]
    const float*  v0f     = (const float*)d_in[2];   // [1, 1, 8, 64] = 512 f32
    float4* out4 = (float4*)d_out;

    const size_t aggFloats = (size_t)NC * Bt * 512;        // 2 MiB
    const size_t sgFloats  = (size_t)(NC / 8) * Bt * 512;  // 256 KiB
    float* aggf   = (float*)d_ws;
    float* sgf    = aggf + aggFloats;
    int*   ticket = (int*)(sgf + sgFloats);

    (void)hipMemsetAsync(aggf, 0xFF, (aggFloats + sgFloats) * sizeof(float), stream);
    (void)hipMemsetAsync(ticket, 0, sizeof(int), stream);

    ema_onepass<<<dim3(NBLK), dim3(NTHR), 0, stream>>>(values4, sw, v0f, out4,
                                                       aggf, sgf, ticket);
}